// Round 1
// 5476.912 us; speedup vs baseline: 1.1610x; 1.1610x over previous
//
#include <hip/hip_runtime.h>

// ---------------------------------------------------------------------------
// 2-layer LSTM (B=256,T=512,H=512,DIN=64) + FC, persistent-kernel wavefront.
// R10: de-LLC the critical sync edge.
//  Evidence (R9 bench): 12.4us/step with MfmaUtil 5.3% -> step time is sync
//  latency, not compute (~1us MFMA) or data (~2us L2). Two ~10us mechanisms
//  sat on the critical edge: (a) RMW-poll serialization at the LLC (64
//  closed-loop fetch_add spinners per cnt line; publisher's +1 queues behind
//  them), (b) RELEASE publish -> buffer_wbl2 whose completion is forced onto
//  the next s_barrier's vmcnt(0) wait.
//  Fix: the critical edge (own-group step s-1) is intra-XCD under the %8
//  dispatch mapping -> per-block FLAG lines in the shared XCD L2 (relaxed
//  store / sc0 multi-lane load poll, ~0.3us). Cross-XCD data freshness comes
//  from SYSTEM-scope (LLC write-through) h-stores: the compiler's vmcnt(0)
//  before s_barrier completes them AT THE LLC before any flag is visible,
//  so no wbl2/release is needed anywhere in the steady loop.
//  Hedges (correct under ANY mapping/semantics):
//   - startup handshake publishes each block's XCC_ID (s_getreg, m09);
//     fast flags enabled only if the whole group shares my XCD.
//   - one-time self-test verifies system-store write-through (checker on a
//     different XCD reads LLC-direct); failure -> publishes revert to the
//     proven RELEASE form (R9 behavior).
//   - fast poll is spin-bounded with permanent fallback to the proven RMW
//     poll. Slack edges (L1<-h0, WAR, FC) keep RMW polls (ring slack hides
//     their latency). Ring rotation + phase-spread acquire-inv unchanged.
// fp16 MFMA (16x16x32), fp32 accum, c-state in registers.
// ---------------------------------------------------------------------------

typedef _Float16 f16;
typedef _Float16 f16x8 __attribute__((ext_vector_type(8)));
typedef float    f32x4 __attribute__((ext_vector_type(4)));

constexpr int NB   = 256;   // batch
constexpr int NT   = 512;   // time steps
constexpr int NH   = 512;   // hidden
constexpr int NDIN = 64;    // input dim

constexpr int L0_KC = 18;   // K chunks of 32: 64(x) + 512(h0) = 576
constexpr int L1_KC = 32;   // 512(h0) + 512(h1) = 1024
constexpr int L0_IMG_HALVES = 4 * L0_KC * 64 * 8;  // 36864 f16 = 73728 B per htile
constexpr int L1_IMG_HALVES = 4 * L1_KC * 64 * 8;  // 65536 f16 = 131072 B per htile

constexpr int RING = 8;     // ring depth (address rotation period)

// ws layout (bytes), all 256-aligned
constexpr size_t BAR_OFF   = 0;                        // cnt[slot][group]: 64 lines * 128 B
constexpr size_t AUX_OFF   = 8192;                     // handshake/self-test lines (4 KB)
constexpr size_t BIAS0_OFF = 16384;                    // 2048 f32
constexpr size_t BIAS1_OFF = 24576;                    // 2048 f32
constexpr size_t FLAG_OFF  = 32768;                    // 256 blocks * 128 B (word0=step, word1=xcd id)
constexpr size_t H0R_OFF   = 65536;                    // [8][256][512] f16 = 2 MB
constexpr size_t H1R_OFF   = H0R_OFF + (size_t)RING * NB * NH * 2;   // + 2MB
constexpr size_t W0I_OFF   = H1R_OFF + (size_t)RING * NB * NH * 2;   // + 2MB
constexpr size_t W1I_OFF   = W0I_OFF + 2359296;        // 32 htiles * 73728 B
constexpr size_t WS_NEED   = W1I_OFF + 4194304;        // ~10.8 MB

// ---------------------------------------------------------------------------
// Prep: swizzle weights (fp32 -> fp16) into MFMA B-fragment order.
// B-frag layout (16x16x32): lane L holds B[k = (L>>4)*8 + j][n = L&15], j=0..7
// Image element order: [htile][nf(=gate)][kc][lane][8 halves]
// ---------------------------------------------------------------------------
__global__ void prep_weights(const float* __restrict__ Wih0, const float* __restrict__ Whh0,
                             const float* __restrict__ Wih1, const float* __restrict__ Whh1,
                             char* __restrict__ ws) {
    int idx = blockIdx.x * 256 + threadIdx.x;
    const int L0_CH = 32 * 4 * L0_KC * 64;   // 147456
    const int L1_CH = 32 * 4 * L1_KC * 64;   // 262144
    if (idx < L0_CH) {
        int lam = idx & 63;
        int kc  = (idx >> 6) % L0_KC;
        int nf  = ((idx >> 6) / L0_KC) & 3;
        int ht  = idx / (64 * L0_KC * 4);
        int g   = nf * NH + ht * 16 + (lam & 15);   // gate row in [0,2048)
        int kb  = kc * 32 + (lam >> 4) * 8;
        f16x8 v;
#pragma unroll
        for (int j = 0; j < 8; ++j) {
            int k = kb + j;
            float val = (k < NDIN) ? Wih0[(size_t)g * NDIN + k]
                                   : Whh0[(size_t)g * NH + (k - NDIN)];
            v[j] = (f16)val;
        }
        f16* dst = (f16*)(ws + W0I_OFF) + (size_t)ht * L0_IMG_HALVES
                 + ((size_t)(nf * L0_KC + kc) * 64 + lam) * 8;
        *(f16x8*)dst = v;
    } else if (idx < L0_CH + L1_CH) {
        int i2  = idx - L0_CH;
        int lam = i2 & 63;
        int kc  = (i2 >> 6) % L1_KC;
        int nf  = ((i2 >> 6) / L1_KC) & 3;
        int ht  = i2 / (64 * L1_KC * 4);
        int g   = nf * NH + ht * 16 + (lam & 15);
        int kb  = kc * 32 + (lam >> 4) * 8;
        f16x8 v;
#pragma unroll
        for (int j = 0; j < 8; ++j) {
            int k = kb + j;
            float val = (k < NH) ? Wih1[(size_t)g * NH + k]
                                 : Whh1[(size_t)g * NH + (k - NH)];
            v[j] = (f16)val;
        }
        f16* dst = (f16*)(ws + W1I_OFF) + (size_t)ht * L1_IMG_HALVES
                 + ((size_t)(nf * L1_KC + kc) * 64 + lam) * 8;
        *(f16x8*)dst = v;
    }
}

// bias sums + zero sync areas (BAR+AUX, FLAG) + zero both h rings (4 MB)
__global__ void prep_state(const float* __restrict__ bih0, const float* __restrict__ bhh0,
                           const float* __restrict__ bih1, const float* __restrict__ bhh1,
                           char* __restrict__ ws) {
    int idx = blockIdx.x * 256 + threadIdx.x;
    const int RINGU4 = (int)((size_t)2 * RING * NB * NH * 2 / 16);   // 262144
    if (idx < 2048) {
        ((float*)(ws + BIAS0_OFF))[idx] = bih0[idx] + bhh0[idx];
    } else if (idx < 4096) {
        int i = idx - 2048;
        ((float*)(ws + BIAS1_OFF))[i] = bih1[i] + bhh1[i];
    } else {
        int c = idx - 4096;
        uint4 z; z.x = z.y = z.z = z.w = 0u;
        if (c < 768) {                                  // BAR (8KB) + AUX (4KB)
            ((uint4*)(ws + BAR_OFF))[c] = z;
        } else if (c < 768 + 2048) {                    // FLAG 32KB
            ((uint4*)(ws + FLAG_OFF))[c - 768] = z;
        } else if (c < 768 + 2048 + RINGU4) {           // h0 + h1 rings contiguous
            ((uint4*)(ws + H0R_OFF))[c - 2816] = z;
        }
    }
}

// ---------------------------------------------------------------------------
// Persistent kernel helpers
// ---------------------------------------------------------------------------
__device__ __forceinline__ float sigf(float x) { return 1.f / (1.f + __expf(-x)); }
__device__ __forceinline__ float tanhx(float x) { float e = __expf(2.f * x); return 1.f - 2.f / (e + 1.f); }

// h stores: SYSTEM scope -> LLC write-through (bypasses L2). vmcnt(0) at the
// trailing __syncthreads completes them AT the LLC -> any later-visible flag
// implies data is globally fresh, with no wbl2/release anywhere in the loop.
__device__ __forceinline__ void h_store(f16* p, float v) {
    unsigned short u = __builtin_bit_cast(unsigned short, (f16)v);
    __hip_atomic_store((unsigned short*)p, u, __ATOMIC_RELAXED, __HIP_MEMORY_SCOPE_SYSTEM);
}

// RMW poll: executes at the LLC (agent-scope atomicity) -> never stale.
// (Used only on slack-tolerant edges and as the E1 fallback.)
template <int SLP>
__device__ __forceinline__ void spin_cnt(unsigned* p, unsigned tgt) {
    while (__hip_atomic_fetch_add(p, 0u, __ATOMIC_RELAXED, __HIP_MEMORY_SCOPE_AGENT) < tgt)
        __builtin_amdgcn_s_sleep(SLP);
}

#define MFMA16(a, b, c) __builtin_amdgcn_mfma_f32_16x16x32_f16((a), (b), (c), 0, 0, 0)

__global__ __launch_bounds__(256, 1) void lstm_persist(char* __restrict__ ws,
                                                       const float* __restrict__ xin,
                                                       const float* __restrict__ fcW,
                                                       const float* __restrict__ fcb,
                                                       float* __restrict__ out) {
    extern __shared__ __align__(16) char smem[];
    f16*   sW   = (f16*)smem;                 // W image: up to 128 KB
    float* exch = (float*)(smem + 131072);    // 8 KB g/o exchange

    const int tid  = threadIdx.x;
    const int lam  = tid & 63;
    const int w    = tid >> 6;
    const int mh   = w & 1;          // M half (rows b0+mh*32 .. +31)
    const int nh   = w >> 1;         // N half: 0 -> gates i,f ; 1 -> gates g,o
    const int col  = lam & 15;
    const int quad = lam >> 4;

    const int bid   = blockIdx.x;
    const int gid   = bid & 7;               // group (XCD-aligned heuristic)
    const int layer = gid >> 2;              // 0..1
    const int b0    = (gid & 3) * 64;        // 4 B-tiles of 64
    const int ht    = bid >> 3;              // 32 H-tiles of 16
    const int h0c   = ht * 16;
    const int KCx   = layer ? L1_KC : L0_KC;

    // cnt line for (group g, ring slot k): one 128B line each
    auto cntp = [&](int g, int slot) -> unsigned* {
        return (unsigned*)(ws + BAR_OFF + (size_t)(slot * 8 + g) * 128);
    };
    unsigned* flags = (unsigned*)(ws + FLAG_OFF);         // 128B line per block
    unsigned* hsk   = (unsigned*)(ws + AUX_OFF);          // startup counter
    unsigned* trdy  = (unsigned*)(ws + AUX_OFF + 128);    // self-test ready
    unsigned* modep = (unsigned*)(ws + AUX_OFF + 256);    // bit1=done, bit0=need_release
    unsigned* finp  = (unsigned*)(ws + AUX_OFF + 384);    // final FC counter
    unsigned* tpat  = (unsigned*)(ws + AUX_OFF + 1024);   // test pattern, 16 words spread over 64B strides

    // ---- startup: XCD-id handshake + write-through self-test (tid 0) ----
    // Done BEFORE W staging so the checker's read window sees a quiet L2
    // (no streaming evictions that could fake a write-through pass).
    if (tid == 0) {
        unsigned myxid = (unsigned)__builtin_amdgcn_s_getreg((31 << 11) | (0 << 6) | 20) & 0xFu; // HW_REG_XCC_ID
        // publish my xid in MY flag line (word 1) -> no false sharing across XCDs
        flags[(size_t)bid * 32 + 1] = myxid;
        __hip_atomic_fetch_add(hsk, 1u, __ATOMIC_RELEASE, __HIP_MEMORY_SCOPE_AGENT);  // flushes xid
        while (__hip_atomic_fetch_add(hsk, 0u, __ATOMIC_RELAXED, __HIP_MEMORY_SCOPE_AGENT) < 256u)
            __builtin_amdgcn_s_sleep(8);
        (void)__hip_atomic_load(hsk, __ATOMIC_ACQUIRE, __HIP_MEMORY_SCOPE_AGENT);     // inv -> fresh table
        unsigned fast = 1u;
        for (int i = 0; i < 32; ++i)
            if (flags[(size_t)(i * 8 + gid) * 32 + 1] != myxid) fast = 0u;
        int chk = 1;
        for (int i = 1; i < 256; ++i)
            if (flags[(size_t)i * 32 + 1] != flags[1]) { chk = i; break; }
        if (bid == 0) {
            for (int i = 0; i < 16; ++i)
                __hip_atomic_store(tpat + i * 16, 0xC0FFEE00u + (unsigned)i,
                                   __ATOMIC_RELAXED, __HIP_MEMORY_SCOPE_SYSTEM);
            asm volatile("s_waitcnt vmcnt(0)" ::: "memory");
            __hip_atomic_fetch_add(trdy, 1u, __ATOMIC_RELAXED, __HIP_MEMORY_SCOPE_AGENT);
        }
        if (bid == chk) {
            while (__hip_atomic_fetch_add(trdy, 0u, __ATOMIC_RELAXED, __HIP_MEMORY_SCOPE_AGENT) < 1u)
                __builtin_amdgcn_s_sleep(8);
            unsigned ok = 1u;   // ANY mismatch -> safe (release) mode
            for (int i = 0; i < 16; ++i)
                if (__hip_atomic_load(tpat + i * 16, __ATOMIC_RELAXED, __HIP_MEMORY_SCOPE_SYSTEM)
                    != 0xC0FFEE00u + (unsigned)i) ok = 0u;
            __hip_atomic_fetch_add(modep, 2u | (ok ? 0u : 1u), __ATOMIC_RELAXED, __HIP_MEMORY_SCOPE_AGENT);
        }
        unsigned mv; int spins = 0;
        while ((mv = __hip_atomic_fetch_add(modep, 0u, __ATOMIC_RELAXED, __HIP_MEMORY_SCOPE_AGENT)) < 2u) {
            __builtin_amdgcn_s_sleep(16);
            if (++spins > (1 << 22)) { mv = 3u; break; }   // timeout -> safe mode
        }
        ((unsigned*)exch)[0] = fast;
        ((unsigned*)exch)[1] = mv & 1u;
    }
    __syncthreads();
    unsigned       fastE1  = ((unsigned*)exch)[0];   // wave0's copy may later flip to 0
    const unsigned needRel = ((unsigned*)exch)[1];
    __syncthreads();

    f16* h0ring = (f16*)(ws + H0R_OFF);
    f16* h1ring = (f16*)(ws + H1R_OFF);
    const float* bias = (const float*)(ws + (layer ? BIAS1_OFF : BIAS0_OFF));
    const f16*   wimg = (const f16*)(ws + (layer ? W1I_OFF : W0I_OFF))
                      + (size_t)ht * (layer ? L1_IMG_HALVES : L0_IMG_HALVES);

    // Stage this block's W slice into LDS once (lives for all 512 steps).
    {
        const int n16 = KCx * 4 * 64;        // uint4 chunks
        const uint4* src = (const uint4*)wimg;
        uint4* dst = (uint4*)sW;
        for (int i = tid; i < n16; i += 256) dst[i] = src[i];
    }
    __syncthreads();

    const float bi_i = bias[0 * NH + h0c + col];
    const float bi_f = bias[1 * NH + h0c + col];
    const float bi_g = bias[2 * NH + h0c + col];
    const float bi_o = bias[3 * NH + h0c + col];

    float cst[2][4];                          // c state (nh==0 waves)
#pragma unroll
    for (int a = 0; a < 2; ++a)
#pragma unroll
        for (int r = 0; r < 4; ++r) cst[a][r] = 0.f;

    const f16x8* sBf = (const f16x8*)sW;
    const int nf0 = nh * 2, nf1 = nh * 2 + 1;
    const int rA0 = b0 + mh * 32 + col;       // A-row for m-frag 0; +16 for frag 1
    constexpr int PREF = 8;

    for (int s = 0; s < NT; ++s) {
        const unsigned us = (unsigned)s;

        // ---- E1 (critical): own group done step s-1.
        // Fast path: multi-lane sc0 poll of the group's 32 flag lines in the
        // shared XCD L2 (~0.3us). Bounded spins -> permanent RMW fallback.
        if (s > 0 && w == 0) {
            if (fastE1) {
                unsigned* fp = flags + (size_t)((lam & 31) * 8 + gid) * 32;
                int tries = 0;
                for (;;) {
                    unsigned v = __hip_atomic_load(fp, __ATOMIC_RELAXED, __HIP_MEMORY_SCOPE_AGENT);
                    if (__all((int)(v >= us))) break;
                    if (++tries > 4096) { fastE1 = 0u; break; }
                    __builtin_amdgcn_s_sleep(1);
                }
            }
            if (!fastE1 && tid == 0)
                spin_cnt<1>(cntp(gid, (s - 1) & 7), 32u * (((us - 1) >> 3) + 1));
        }
        // ---- slack edges: LLC RMW polls (ring slack hides their latency) ----
        if (layer == 0) {
            // WAR (slack 8): L1 partner done step s-8 (we overwrite h0 slot s&7)
            if (tid == 64 && s >= RING)
                spin_cnt<8>(cntp(gid + 4, s & 7), 32u * (us >> 3));
        } else {
            // L0 partner done step s (h0[s] ready; L0 runs ahead -> usually satisfied)
            if (tid == 64)
                spin_cnt<4>(cntp(gid - 4, s & 7), 32u * ((us >> 3) + 1));
        }
        __syncthreads();

        // ---- gate GEMM (PLAIN loads; slot addresses unseen for 8 steps ->
        // compulsory L2 miss -> fresh from LLC, then L2-served broadcast) ----
        f32x4 acc00 = {0.f,0.f,0.f,0.f}, acc01 = {0.f,0.f,0.f,0.f};
        f32x4 acc10 = {0.f,0.f,0.f,0.f}, acc11 = {0.f,0.f,0.f,0.f};

        if (layer == 0) {
            const f16* hp = h0ring + (size_t)((s - 1) & 7) * (NB * NH);   // s=0 -> slot 7 (zeros)
            auto ldX = [&](int row, int kc) -> f16x8 {
                const float* xr = xin + (size_t)row * (NT * NDIN) + (size_t)s * NDIN + kc * 32 + quad * 8;
                float4 f0 = *(const float4*)xr;
                float4 f1 = *(const float4*)(xr + 4);
                f16x8 v;
                v[0] = (f16)f0.x; v[1] = (f16)f0.y; v[2] = (f16)f0.z; v[3] = (f16)f0.w;
                v[4] = (f16)f1.x; v[5] = (f16)f1.y; v[6] = (f16)f1.z; v[7] = (f16)f1.w;
                return v;
            };
            auto ldA0 = [&](int kc) -> f16x8 {
                return (kc < 2) ? ldX(rA0, kc)
                                : *(const f16x8*)(hp + (size_t)rA0 * NH + (kc - 2) * 32 + quad * 8);
            };
            auto ldA1 = [&](int kc) -> f16x8 {
                return (kc < 2) ? ldX(rA0 + 16, kc)
                                : *(const f16x8*)(hp + (size_t)(rA0 + 16) * NH + (kc - 2) * 32 + quad * 8);
            };
            f16x8 pa[PREF], pb[PREF];
#pragma unroll
            for (int p = 0; p < PREF; ++p) { pa[p] = ldA0(p); pb[p] = ldA1(p); }
#pragma unroll
            for (int kc = 0; kc < L0_KC; ++kc) {
                f16x8 a0 = pa[kc & (PREF - 1)], a1 = pb[kc & (PREF - 1)];
                if (kc + PREF < L0_KC) { pa[kc & (PREF - 1)] = ldA0(kc + PREF); pb[kc & (PREF - 1)] = ldA1(kc + PREF); }
                f16x8 w0 = sBf[(nf0 * L0_KC + kc) * 64 + lam];
                f16x8 w1 = sBf[(nf1 * L0_KC + kc) * 64 + lam];
                acc00 = MFMA16(a0, w0, acc00);
                acc01 = MFMA16(a0, w1, acc01);
                acc10 = MFMA16(a1, w0, acc10);
                acc11 = MFMA16(a1, w1, acc11);
            }
        } else {
            const f16* hp0 = h0ring + (size_t)(s & 7) * (NB * NH);        // h0[s]
            const f16* hp1 = h1ring + (size_t)((s - 1) & 7) * (NB * NH);  // h1[s-1]; s=0 -> slot 7 (zeros)
            auto ldA0 = [&](int kc) -> f16x8 {
                return (kc < 16) ? *(const f16x8*)(hp0 + (size_t)rA0 * NH + kc * 32 + quad * 8)
                                 : *(const f16x8*)(hp1 + (size_t)rA0 * NH + (kc - 16) * 32 + quad * 8);
            };
            auto ldA1 = [&](int kc) -> f16x8 {
                return (kc < 16) ? *(const f16x8*)(hp0 + (size_t)(rA0 + 16) * NH + kc * 32 + quad * 8)
                                 : *(const f16x8*)(hp1 + (size_t)(rA0 + 16) * NH + (kc - 16) * 32 + quad * 8);
            };
            f16x8 pa[PREF], pb[PREF];
#pragma unroll
            for (int p = 0; p < PREF; ++p) { pa[p] = ldA0(p); pb[p] = ldA1(p); }
#pragma unroll
            for (int kc = 0; kc < L1_KC; ++kc) {
                f16x8 a0 = pa[kc & (PREF - 1)], a1 = pb[kc & (PREF - 1)];
                if (kc + PREF < L1_KC) { pa[kc & (PREF - 1)] = ldA0(kc + PREF); pb[kc & (PREF - 1)] = ldA1(kc + PREF); }
                f16x8 w0 = sBf[(nf0 * L1_KC + kc) * 64 + lam];
                f16x8 w1 = sBf[(nf1 * L1_KC + kc) * 64 + lam];
                acc00 = MFMA16(a0, w0, acc00);
                acc01 = MFMA16(a0, w1, acc01);
                acc10 = MFMA16(a1, w0, acc10);
                acc11 = MFMA16(a1, w1, acc11);
            }
        }

        // g/o waves hand their accs to i/f waves; cell update is register-local there.
        if (nh == 1) {
            f32x4* e4 = (f32x4*)exch;
            e4[((mh * 2 + 0) * 2 + 0) * 64 + lam] = acc00;   // mf0, gate g
            e4[((mh * 2 + 0) * 2 + 1) * 64 + lam] = acc01;   // mf0, gate o
            e4[((mh * 2 + 1) * 2 + 0) * 64 + lam] = acc10;   // mf1, gate g
            e4[((mh * 2 + 1) * 2 + 1) * 64 + lam] = acc11;   // mf1, gate o
        }
        __syncthreads();   // all waves' A-loads consumed beyond this point

        // ---- staleness bound: one acquire-inv per block every RING steps,
        // phase-spread by ht, post-consumption (off the critical detect path).
        // Guarantees: any ring line we cached >= 8 steps ago is evicted before
        // that slot's addresses are re-consumed. (inv drops clean lines only,
        // so same-XCD dirty data in safe mode is never lost.)
        if (tid == 128 && ((s & 7) == (ht & 7)))
            (void)__hip_atomic_load((unsigned*)(ws + BAR_OFF), __ATOMIC_ACQUIRE, __HIP_MEMORY_SCOPE_AGENT);

        if (nh == 0) {
            const f32x4* e4 = (const f32x4*)exch;
            f32x4 gg0 = e4[((mh * 2 + 0) * 2 + 0) * 64 + lam];
            f32x4 oo0 = e4[((mh * 2 + 0) * 2 + 1) * 64 + lam];
            f32x4 gg1 = e4[((mh * 2 + 1) * 2 + 0) * 64 + lam];
            f32x4 oo1 = e4[((mh * 2 + 1) * 2 + 1) * 64 + lam];
            f16* hw = (layer ? h1ring : h0ring) + (size_t)(s & 7) * (NB * NH);
#pragma unroll
            for (int mf = 0; mf < 2; ++mf) {
                f32x4 ai = mf ? acc10 : acc00;
                f32x4 af = mf ? acc11 : acc01;
                f32x4 ag = mf ? gg1 : gg0;
                f32x4 ao = mf ? oo1 : oo0;
#pragma unroll
                for (int r = 0; r < 4; ++r) {
                    float iv = ai[r] + bi_i;
                    float fv = af[r] + bi_f;
                    float gv = ag[r] + bi_g;
                    float ov = ao[r] + bi_o;
                    float cc = sigf(fv) * cst[mf][r] + sigf(iv) * tanhx(gv);
                    cst[mf][r] = cc;
                    float hh = sigf(ov) * tanhx(cc);
                    // C/D layout: row = quad*4 + r, col = lane&15
                    h_store(&hw[(size_t)(b0 + mh * 32 + mf * 16 + quad * 4 + r) * NH + h0c + col], hh);
                }
            }
        }

        // ---- publish: the barrier drains all h-stores (vmcnt(0) before
        // s_barrier -> SYSTEM stores complete AT the LLC). Then wave 3 (never
        // a poller) posts: relaxed flag store (L2 fast path) + cnt RMW at the
        // LLC for slack/fallback consumers. RELEASE (wbl2) only if the
        // self-test found system stores don't write through.
        __syncthreads();
        if (tid == 192) {
            __hip_atomic_store(flags + (size_t)bid * 32, us + 1u,
                               __ATOMIC_RELAXED, __HIP_MEMORY_SCOPE_AGENT);
            if (needRel)
                __hip_atomic_fetch_add(cntp(gid, s & 7), 1u, __ATOMIC_RELEASE, __HIP_MEMORY_SCOPE_AGENT);
            else
                __hip_atomic_fetch_add(cntp(gid, s & 7), 1u, __ATOMIC_RELAXED, __HIP_MEMORY_SCOPE_AGENT);
        }
    }

    // L1 blocks: one final RELEASE publish (flushes h1 to LLC even in safe
    // mode; harmless wbl2 once) so the FC reader is correct either way.
    if (layer == 1 && tid == 0)
        __hip_atomic_fetch_add(finp, 1u, __ATOMIC_RELEASE, __HIP_MEMORY_SCOPE_AGENT);

    // Final FC by block 0: all 128 L1 blocks must have finished step 511.
    if (bid == 0) {
        if (tid == 0) {
            while (__hip_atomic_fetch_add(finp, 0u, __ATOMIC_RELAXED, __HIP_MEMORY_SCOPE_AGENT) < 128u)
                __builtin_amdgcn_s_sleep(8);
            (void)__hip_atomic_load((unsigned*)(ws + BAR_OFF), __ATOMIC_ACQUIRE, __HIP_MEMORY_SCOPE_AGENT);
        }
        __syncthreads();
        const f16* hrow = h1ring + (size_t)7 * (NB * NH) + (size_t)tid * NH;  // slot 511&7 = 7
        float acc = fcb[0];
#pragma unroll 4
        for (int j = 0; j < NH; j += 8) {
            f16x8 hv = *(const f16x8*)(hrow + j);
#pragma unroll
            for (int e = 0; e < 8; ++e) acc += fcW[j + e] * (float)hv[e];
        }
        out[tid] = acc;
    }
}

// ---------------------------------------------------------------------------
extern "C" void kernel_launch(void* const* d_in, const int* in_sizes, int n_in,
                              void* d_out, int out_size, void* d_ws, size_t ws_size,
                              hipStream_t stream) {
    const float* x    = (const float*)d_in[0];
    const float* Wih0 = (const float*)d_in[1];
    const float* Whh0 = (const float*)d_in[2];
    const float* bih0 = (const float*)d_in[3];
    const float* bhh0 = (const float*)d_in[4];
    const float* Wih1 = (const float*)d_in[5];
    const float* Whh1 = (const float*)d_in[6];
    const float* bih1 = (const float*)d_in[7];
    const float* bhh1 = (const float*)d_in[8];
    const float* fcW  = (const float*)d_in[9];
    const float* fcb  = (const float*)d_in[10];
    char*  ws  = (char*)d_ws;
    float* out = (float*)d_out;

    if (ws_size < WS_NEED) {  // deterministic failure instead of corruption
        hipMemsetAsync(d_out, 0, (size_t)out_size * sizeof(float), stream);
        return;
    }

    hipFuncSetAttribute(reinterpret_cast<const void*>(lstm_persist),
                        hipFuncAttributeMaxDynamicSharedMemorySize, 139264);

    prep_weights<<<1600, 256, 0, stream>>>(Wih0, Whh0, Wih1, Whh1, ws);
    prep_state<<<1100, 256, 0, stream>>>(bih0, bhh0, bih1, bhh1, ws);
    // 256 blocks, 139264 B dynamic LDS -> exactly 1 block/CU on 256 CUs
    lstm_persist<<<256, 256, 139264, stream>>>(ws, x, fcW, fcb, out);
}